// Round 10
// baseline (496.597 us; speedup 1.0000x reference)
//
#include <hip/hip_runtime.h>
#include <hip/hip_bf16.h>

// 1-NN VQ via split-bf16 MFMA + exact fp32 refinement.
//   score[q][k] = csq[k] - 2*dot(q,c_k); out = argmin_k (lowest-k tie-break).
// Phase 0 (knn_prep): codebook -> bf16 hi/lo fragment-ready cbB (part-major) + csq.
// Phase A (knn_mfma): 128 q/block, 4 waves; wave = 2 m-tiles x ALL 16 n-tiles
//   (acc[2][16] = 128 AGPR). A split-converted ONCE to regs (ah/al[2][4] =
//   64 VGPR). B read straight from L2 (global b128, 16 independent loads per
//   kb -> deep vmcnt pipeline). NO LDS in main loop, NO barriers after
//   prologue. dot ~= qh.ch + ql.ch + qh.cl (3-product, score err ~1.9e-3);
//   per-wave top-2 over all 256 codes; gap < T=0.004 -> worklist.
// Phase B (knn_refine): exact fp32 rescan, block-per-query.
// r10 vs r9: r9's B-in-LDS halved B-reuse AND left ~2 spare VGPRs -> ds_reads
//   went single-outstanding (~120cyc, MfmaUtil 9.7%). r6 (B from L2) was the
//   best measured structure (62-70us profiled) but had per-kb A-conv VALU
//   pollution (VALUBusy 35%); r9 proved A-hoist fixes that (18%). r10 = both.
//   Known-good budget: ~120 VGPR + 128 AGPR at 2 waves/SIMD (r9 measured).

typedef __bf16 bf16x8 __attribute__((ext_vector_type(8)));
typedef float  floatx4 __attribute__((ext_vector_type(4)));

#define MFMA16 __builtin_amdgcn_mfma_f32_16x16x32_bf16

#define CNT_OFF 0
#define CSQ_OFF 1024
#define CBB_OFF 4096
#define WL_OFF  (4096 + 131072)
#define WL_CAP  32768
#define T_FLAG  0.004f

__device__ __forceinline__ unsigned fmap(float f) {
    unsigned u = __float_as_uint(f);
    return (u & 0x80000000u) ? ~u : (u | 0x80000000u);
}
__device__ __forceinline__ float unfmap(unsigned u) {
    unsigned b = (u & 0x80000000u) ? (u ^ 0x80000000u) : ~u;
    return __uint_as_float(b);
}

// ---------------- Phase 0: codebook split, part-major fragment layout, csq ----------------
// cbB element index = part*32768 + ((t4*4 + kb)*64 + ln)*8 + j
//   part: 0=hi 1=lo; t4 = ntile 0..15; kb = k-chunk 0..3;
//   lane ln: n = t4*16 + (ln&15), k = kb*32 + (ln>>4)*8 + j.
__global__ void knn_prep(const float* __restrict__ cb, __bf16* __restrict__ cbB,
                         float* __restrict__ csq, int* __restrict__ cnt) {
    const int tid = threadIdx.x;
    const int id = blockIdx.x * 256 + tid;       // 0..8191
    if (id == 0) *cnt = 0;
    const int part = id >> 12;
    const int rem = id & 4095;
    const int t4 = rem >> 8;
    const int kb = (rem >> 6) & 3;
    const int ln = id & 63;
    const int n = t4 * 16 + (ln & 15);
    const int k0 = kb * 32 + (ln >> 4) * 8;
    const float* src = cb + (size_t)n * 128 + k0;
    union { __bf16 h[8]; uint4 u; } p;
#pragma unroll
    for (int j = 0; j < 8; ++j) {
        float f = src[j];
        __bf16 hh = (__bf16)f;
        p.h[j] = (part == 0) ? hh : (__bf16)(f - (float)hh);
    }
    *(uint4*)(cbB + (size_t)id * 8) = p.u;

    if (blockIdx.x == 0) {
        const float4* row = (const float4*)(cb + (size_t)tid * 128);
        float a0 = 0.f, a1 = 0.f, a2 = 0.f, a3 = 0.f;
#pragma unroll 8
        for (int j = 0; j < 32; ++j) {
            float4 v = row[j];
            a0 = fmaf(v.x, v.x, a0);
            a1 = fmaf(v.y, v.y, a1);
            a2 = fmaf(v.z, v.z, a2);
            a3 = fmaf(v.w, v.w, a3);
        }
        csq[tid] = (a0 + a1) + (a2 + a3);
    }
}

// ---------------- Phase A: MFMA scores + top-2 + flag ----------------
__global__ __launch_bounds__(256, 2) void knn_mfma(const float* __restrict__ x,
                                                   const __bf16* __restrict__ cbB,
                                                   const float* __restrict__ csq_g,
                                                   int* __restrict__ out,
                                                   int* __restrict__ cnt,
                                                   int* __restrict__ wl) {
    __shared__ float s_csq[256];                 // 1 KB (only LDS in kernel)

    const int tid = threadIdx.x;
    const int wave = tid >> 6;
    const int lane = tid & 63;
    const int rl = lane & 15;                    // m/n col within tile
    const int kg = lane >> 4;                    // k-group 0..3

    s_csq[tid] = csq_g[tid];
    __syncthreads();

    // ---- A: load + split-convert this wave's 2 m-tiles into registers ----
    const float* xq = x + ((size_t)blockIdx.x * 128 + wave * 32) * 128;
    bf16x8 ah[2][4], al[2][4];
#pragma unroll
    for (int m = 0; m < 2; ++m) {
#pragma unroll
        for (int kb = 0; kb < 4; ++kb) {
            const float* s = xq + (size_t)(m * 16 + rl) * 128 + kb * 32 + kg * 8;
            float4 f0 = *(const float4*)(s);
            float4 f1 = *(const float4*)(s + 4);
            float f[8] = {f0.x, f0.y, f0.z, f0.w, f1.x, f1.y, f1.z, f1.w};
            union { __bf16 h[8]; bf16x8 v; } ph, pl;
#pragma unroll
            for (int j = 0; j < 8; ++j) {
                __bf16 hh = (__bf16)f[j];
                ph.h[j] = hh;
                pl.h[j] = (__bf16)(f[j] - (float)hh);
            }
            ah[m][kb] = ph.v;
            al[m][kb] = pl.v;
        }
    }

    floatx4 acc[2][16];
#pragma unroll
    for (int m = 0; m < 2; ++m)
#pragma unroll
        for (int t = 0; t < 16; ++t) acc[m][t] = (floatx4){0.f, 0.f, 0.f, 0.f};

    // ---- hi phase: qh.ch + ql.ch ; B straight from L2 ----
#pragma unroll 1
    for (int kb = 0; kb < 4; ++kb) {
#pragma unroll
        for (int t = 0; t < 16; ++t) {
            bf16x8 b = *(const bf16x8*)(cbB + (((t * 4 + kb) * 64 + lane) * 8));
            acc[0][t] = MFMA16(ah[0][kb], b, acc[0][t], 0, 0, 0);
            acc[1][t] = MFMA16(ah[1][kb], b, acc[1][t], 0, 0, 0);
            acc[0][t] = MFMA16(al[0][kb], b, acc[0][t], 0, 0, 0);
            acc[1][t] = MFMA16(al[1][kb], b, acc[1][t], 0, 0, 0);
        }
    }

    // ---- lo phase: qh.cl only (ql.cl dropped) ----
#pragma unroll 1
    for (int kb = 0; kb < 4; ++kb) {
#pragma unroll
        for (int t = 0; t < 16; ++t) {
            bf16x8 b = *(const bf16x8*)(cbB + 32768
                                        + (((t * 4 + kb) * 64 + lane) * 8));
            acc[0][t] = MFMA16(ah[0][kb], b, acc[0][t], 0, 0, 0);
            acc[1][t] = MFMA16(ah[1][kb], b, acc[1][t], 0, 0, 0);
        }
    }

    // ---- epilogue: per-wave top-2 over ALL 256 codes (FULLY unrolled) ----
    float cs[16];
#pragma unroll
    for (int t = 0; t < 16; ++t) cs[t] = s_csq[t * 16 + rl];

#pragma unroll
    for (int m = 0; m < 2; ++m) {
#pragma unroll
        for (int r = 0; r < 4; ++r) {
            unsigned long long b = ~0ULL, s = ~0ULL;
#pragma unroll
            for (int t = 0; t < 16; ++t) {
                const int n = t * 16 + rl;
                float score = fmaf(-2.0f, acc[m][t][r], cs[t]);
                unsigned long long key =
                    ((unsigned long long)fmap(score) << 32) | (unsigned)n;
                if (key < b) { s = b; b = key; }
                else if (key < s) { s = key; }
            }
#pragma unroll
            for (int d = 1; d < 16; d <<= 1) {
                unsigned long long ob = __shfl_xor(b, d);
                unsigned long long os = __shfl_xor(s, d);
                unsigned long long nb = ob < b ? ob : b;
                unsigned long long mx = ob < b ? b : ob;
                unsigned long long mn = os < s ? os : s;
                b = nb;
                s = mx < mn ? mx : mn;
            }
            if (rl == 0) {
                const size_t qg = (size_t)blockIdx.x * 128 + wave * 32
                                  + m * 16 + kg * 4 + r;
                out[qg] = (int)(unsigned)(b & 0xFFFFFFFFull);
                float f1 = unfmap((unsigned)(b >> 32));
                float f2 = unfmap((unsigned)(s >> 32));
                if (f2 - f1 < T_FLAG) {
                    int idx = atomicAdd(cnt, 1);
                    if (idx < WL_CAP) wl[idx] = (int)qg;
                }
            }
        }
    }
}

// ---------------- Phase B: exact fp32 rescan, block-per-query ----------------
__global__ __launch_bounds__(256) void knn_refine(const float* __restrict__ x,
                                                  const float* __restrict__ cb,
                                                  const float* __restrict__ csq_g,
                                                  const int* __restrict__ wl,
                                                  const int* __restrict__ cnt,
                                                  int* __restrict__ out) {
    __shared__ unsigned long long sP[4];
    const int tid = threadIdx.x;           // == code index k
    const int lane = tid & 63;
    const int wave = tid >> 6;

    int n = *cnt;
    if (n > WL_CAP) n = WL_CAP;
    const float mycsq = csq_g[tid];
    const float4* cr = (const float4*)(cb + (size_t)tid * 128);

    for (int i = blockIdx.x; i < n; i += gridDim.x) {
        const int q = wl[i];
        const float4* qr = (const float4*)(x + (size_t)q * 128);
        float a0 = 0.f, a1 = 0.f, a2 = 0.f, a3 = 0.f;
#pragma unroll 8
        for (int c4 = 0; c4 < 32; ++c4) {
            float4 qv = qr[c4];            // broadcast (same addr all lanes)
            float4 cv = cr[c4];
            a0 = fmaf(qv.x, cv.x, a0);
            a1 = fmaf(qv.y, cv.y, a1);
            a2 = fmaf(qv.z, cv.z, a2);
            a3 = fmaf(qv.w, cv.w, a3);
        }
        float dot = (a0 + a1) + (a2 + a3);
        float score = fmaf(-2.0f, dot, mycsq);
        unsigned long long key =
            ((unsigned long long)fmap(score) << 32) | (unsigned)tid;
#pragma unroll
        for (int d = 1; d < 64; d <<= 1) {
            unsigned long long o = __shfl_xor(key, d);
            key = o < key ? o : key;
        }
        if (lane == 0) sP[wave] = key;
        __syncthreads();
        if (tid == 0) {
            unsigned long long b = sP[0];
            unsigned long long o;
            o = sP[1]; b = o < b ? o : b;
            o = sP[2]; b = o < b ? o : b;
            o = sP[3]; b = o < b ? o : b;
            out[q] = (int)(unsigned)(b & 0xFFFFFFFFull);
        }
        __syncthreads();
    }
}

extern "C" void kernel_launch(void* const* d_in, const int* in_sizes, int n_in,
                              void* d_out, int out_size, void* d_ws, size_t ws_size,
                              hipStream_t stream) {
    const float* x = (const float*)d_in[0];
    const float* cb = (const float*)d_in[1];
    int* out = (int*)d_out;

    char* ws = (char*)d_ws;
    int* cnt = (int*)(ws + CNT_OFF);
    float* csq = (float*)(ws + CSQ_OFF);
    __bf16* cbB = (__bf16*)(ws + CBB_OFF);
    int* wl = (int*)(ws + WL_OFF);

    const int M = in_sizes[0] / 128;     // 131072

    knn_prep<<<32, 256, 0, stream>>>(cb, cbB, csq, cnt);
    knn_mfma<<<M / 128, 256, 0, stream>>>(x, cbB, csq, out, cnt, wl);
    knn_refine<<<240, 256, 0, stream>>>(x, cb, csq, wl, cnt, out);
}

// Round 11
// 145.292 us; speedup vs baseline: 3.4179x; 3.4179x over previous
//
#include <hip/hip_runtime.h>
#include <hip/hip_bf16.h>

// 1-NN VQ via split-bf16 MFMA + exact fp32 refinement.
//   score[q][k] = csq[k] - 2*dot(q,c_k); out = argmin_k (lowest-k tie-break).
// Phase 0 (knn_prep): codebook -> bf16 hi/lo fragment-ready cbB (part-major) + csq.
// Phase A (knn_mfma): 64 q/block, 4 waves = 2 mgroups x 2 ngroups.
//   Wave = 2 m-tiles x 8 n-tiles: acc[2][8] = 64 AGPR ONLY. A split-converted
//   once to regs (ah/al[2][4] = 64 VGPR, r9-proven no-spill). B staged hi->lo
//   in 64 KB LDS (r8 staging). ~85 spare regs -> ds_reads pipeline.
//   dot ~= qh.ch + ql.ch + qh.cl (3-product, score err ~1.9e-3); per-wave
//   top-2 over 128 codes, ngroup merge in LDS (r8 epilogue, absmax-0-proven);
//   gap < T=0.004 -> worklist.
// Phase B (knn_refine): exact fp32 rescan, block-per-query.
// Register-budget ledger (the whole game, rounds 2-10):
//   r9:  A64 + acc128 + LDS-B  -> fits, 2 spare  -> ds_read serialization (97us)
//   r10: A64 + acc128 + L2-B   -> spill (WRITE 237 MB, 423us)
//   r11: A64 + acc64  + LDS-B  -> ~85 spare -> pipelined.  <- this kernel

typedef __bf16 bf16x8 __attribute__((ext_vector_type(8)));
typedef float  floatx4 __attribute__((ext_vector_type(4)));

#define MFMA16 __builtin_amdgcn_mfma_f32_16x16x32_bf16

#define CNT_OFF 0
#define CSQ_OFF 1024
#define CBB_OFF 4096
#define WL_OFF  (4096 + 131072)
#define WL_CAP  32768
#define T_FLAG  0.004f

__device__ __forceinline__ unsigned fmap(float f) {
    unsigned u = __float_as_uint(f);
    return (u & 0x80000000u) ? ~u : (u | 0x80000000u);
}
__device__ __forceinline__ float unfmap(unsigned u) {
    unsigned b = (u & 0x80000000u) ? (u ^ 0x80000000u) : ~u;
    return __uint_as_float(b);
}

// ---------------- Phase 0: codebook split, part-major fragment layout, csq ----------------
// cbB element index = part*32768 + ((t4*4 + kb)*64 + ln)*8 + j
//   part: 0=hi 1=lo; t4 = ntile 0..15; kb = k-chunk 0..3;
//   lane ln: n = t4*16 + (ln&15), k = kb*32 + (ln>>4)*8 + j.
__global__ void knn_prep(const float* __restrict__ cb, __bf16* __restrict__ cbB,
                         float* __restrict__ csq, int* __restrict__ cnt) {
    const int tid = threadIdx.x;
    const int id = blockIdx.x * 256 + tid;       // 0..8191
    if (id == 0) *cnt = 0;
    const int part = id >> 12;
    const int rem = id & 4095;
    const int t4 = rem >> 8;
    const int kb = (rem >> 6) & 3;
    const int ln = id & 63;
    const int n = t4 * 16 + (ln & 15);
    const int k0 = kb * 32 + (ln >> 4) * 8;
    const float* src = cb + (size_t)n * 128 + k0;
    union { __bf16 h[8]; uint4 u; } p;
#pragma unroll
    for (int j = 0; j < 8; ++j) {
        float f = src[j];
        __bf16 hh = (__bf16)f;
        p.h[j] = (part == 0) ? hh : (__bf16)(f - (float)hh);
    }
    *(uint4*)(cbB + (size_t)id * 8) = p.u;

    if (blockIdx.x == 0) {
        const float4* row = (const float4*)(cb + (size_t)tid * 128);
        float a0 = 0.f, a1 = 0.f, a2 = 0.f, a3 = 0.f;
#pragma unroll 8
        for (int j = 0; j < 32; ++j) {
            float4 v = row[j];
            a0 = fmaf(v.x, v.x, a0);
            a1 = fmaf(v.y, v.y, a1);
            a2 = fmaf(v.z, v.z, a2);
            a3 = fmaf(v.w, v.w, a3);
        }
        csq[tid] = (a0 + a1) + (a2 + a3);
    }
}

// ---------------- Phase A: MFMA scores + top-2 + flag ----------------
__global__ __launch_bounds__(256, 2) void knn_mfma(const float* __restrict__ x,
                                                   const __bf16* __restrict__ cbB,
                                                   const float* __restrict__ csq_g,
                                                   int* __restrict__ out,
                                                   int* __restrict__ cnt,
                                                   int* __restrict__ wl) {
    __shared__ __bf16 sB[32768];                 // 64 KB: current B part
    __shared__ float s_csq[256];                 // 1 KB
    __shared__ unsigned long long sWb[128];      // 1 KB: [ql][ng] best
    __shared__ unsigned long long sWs[128];      // 1 KB: [ql][ng] second

    const int tid = threadIdx.x;
    const int wave = tid >> 6;
    const int lane = tid & 63;
    const int mg = wave >> 1;                    // m-group 0..1
    const int ng = wave & 1;                     // n-group 0..1
    const int rl = lane & 15;                    // m/n col within tile
    const int kg = lane >> 4;                    // k/row group 0..3

    s_csq[tid] = csq_g[tid];

    // ---- A: load + split-convert this wave's 2 m-tiles into registers ----
    const float* xq = x + ((size_t)blockIdx.x * 64 + mg * 32) * 128;
    bf16x8 ah[2][4], al[2][4];
#pragma unroll
    for (int m = 0; m < 2; ++m) {
#pragma unroll
        for (int kb = 0; kb < 4; ++kb) {
            const float* s = xq + (size_t)(m * 16 + rl) * 128 + kb * 32 + kg * 8;
            float4 f0 = *(const float4*)(s);
            float4 f1 = *(const float4*)(s + 4);
            float f[8] = {f0.x, f0.y, f0.z, f0.w, f1.x, f1.y, f1.z, f1.w};
            union { __bf16 h[8]; bf16x8 v; } ph, pl;
#pragma unroll
            for (int j = 0; j < 8; ++j) {
                __bf16 hh = (__bf16)f[j];
                ph.h[j] = hh;
                pl.h[j] = (__bf16)(f[j] - (float)hh);
            }
            ah[m][kb] = ph.v;
            al[m][kb] = pl.v;
        }
    }

    // ---- stage B hi (64 KB) ----
    {
        const uint4* src = (const uint4*)cbB;    // part 0
        uint4* dst = (uint4*)sB;
#pragma unroll 4
        for (int i = 0; i < 16; ++i) dst[i * 256 + tid] = src[i * 256 + tid];
    }
    __syncthreads();

    floatx4 acc[2][8];
#pragma unroll
    for (int m = 0; m < 2; ++m)
#pragma unroll
        for (int t = 0; t < 8; ++t) acc[m][t] = (floatx4){0.f, 0.f, 0.f, 0.f};

    // ---- hi phase: qh.ch + ql.ch ----
#pragma unroll
    for (int kb = 0; kb < 4; ++kb) {
#pragma unroll
        for (int t = 0; t < 8; ++t) {
            const int t4 = ng * 8 + t;
            bf16x8 b = *(const bf16x8*)(sB + (((t4 * 4 + kb) * 64 + lane) * 8));
            acc[0][t] = MFMA16(ah[0][kb], b, acc[0][t], 0, 0, 0);
            acc[1][t] = MFMA16(ah[1][kb], b, acc[1][t], 0, 0, 0);
            acc[0][t] = MFMA16(al[0][kb], b, acc[0][t], 0, 0, 0);
            acc[1][t] = MFMA16(al[1][kb], b, acc[1][t], 0, 0, 0);
        }
    }
    __syncthreads();   // hi reads done before overwrite

    // ---- stage B lo (64 KB) ----
    {
        const uint4* src = (const uint4*)(cbB + 32768);   // part 1
        uint4* dst = (uint4*)sB;
#pragma unroll 4
        for (int i = 0; i < 16; ++i) dst[i * 256 + tid] = src[i * 256 + tid];
    }
    __syncthreads();

    // ---- lo phase: qh.cl only (ql.cl dropped) ----
#pragma unroll
    for (int kb = 0; kb < 4; ++kb) {
#pragma unroll
        for (int t = 0; t < 8; ++t) {
            const int t4 = ng * 8 + t;
            bf16x8 b = *(const bf16x8*)(sB + (((t4 * 4 + kb) * 64 + lane) * 8));
            acc[0][t] = MFMA16(ah[0][kb], b, acc[0][t], 0, 0, 0);
            acc[1][t] = MFMA16(ah[1][kb], b, acc[1][t], 0, 0, 0);
        }
    }

    // ---- epilogue: per-wave top-2 over its 128 codes (FULLY unrolled) ----
    float cs[8];
#pragma unroll
    for (int t = 0; t < 8; ++t) cs[t] = s_csq[(ng * 8 + t) * 16 + rl];

#pragma unroll
    for (int m = 0; m < 2; ++m) {
#pragma unroll
        for (int r = 0; r < 4; ++r) {
            unsigned long long b = ~0ULL, s = ~0ULL;
#pragma unroll
            for (int t = 0; t < 8; ++t) {
                const int n = (ng * 8 + t) * 16 + rl;
                float score = fmaf(-2.0f, acc[m][t][r], cs[t]);
                unsigned long long key =
                    ((unsigned long long)fmap(score) << 32) | (unsigned)n;
                if (key < b) { s = b; b = key; }
                else if (key < s) { s = key; }
            }
#pragma unroll
            for (int d = 1; d < 16; d <<= 1) {
                unsigned long long ob = __shfl_xor(b, d);
                unsigned long long os = __shfl_xor(s, d);
                unsigned long long nb = ob < b ? ob : b;
                unsigned long long mx = ob < b ? b : ob;
                unsigned long long mn = os < s ? os : s;
                b = nb;
                s = mx < mn ? mx : mn;
            }
            if (rl == 0) {
                const int ql = mg * 32 + m * 16 + kg * 4 + r;   // 0..63
                sWb[ql * 2 + ng] = b;
                sWs[ql * 2 + ng] = s;
            }
        }
    }
    __syncthreads();

    // ---- merge the 2 n-groups, write out, flag near-ties ----
    if (tid < 64) {
        unsigned long long b0 = sWb[tid * 2 + 0], b1 = sWb[tid * 2 + 1];
        unsigned long long s0 = sWs[tid * 2 + 0], s1 = sWs[tid * 2 + 1];
        unsigned long long best = b0 < b1 ? b0 : b1;
        unsigned long long mx = b0 < b1 ? b1 : b0;
        unsigned long long mn = s0 < s1 ? s0 : s1;
        unsigned long long sec = mx < mn ? mx : mn;
        const size_t qg = (size_t)blockIdx.x * 64 + tid;
        out[qg] = (int)(unsigned)(best & 0xFFFFFFFFull);
        float f1 = unfmap((unsigned)(best >> 32));
        float f2 = unfmap((unsigned)(sec >> 32));
        if (f2 - f1 < T_FLAG) {
            int idx = atomicAdd(cnt, 1);
            if (idx < WL_CAP) wl[idx] = (int)qg;
        }
    }
}

// ---------------- Phase B: exact fp32 rescan, block-per-query ----------------
__global__ __launch_bounds__(256) void knn_refine(const float* __restrict__ x,
                                                  const float* __restrict__ cb,
                                                  const float* __restrict__ csq_g,
                                                  const int* __restrict__ wl,
                                                  const int* __restrict__ cnt,
                                                  int* __restrict__ out) {
    __shared__ unsigned long long sP[4];
    const int tid = threadIdx.x;           // == code index k
    const int lane = tid & 63;
    const int wave = tid >> 6;

    int n = *cnt;
    if (n > WL_CAP) n = WL_CAP;
    const float mycsq = csq_g[tid];
    const float4* cr = (const float4*)(cb + (size_t)tid * 128);

    for (int i = blockIdx.x; i < n; i += gridDim.x) {
        const int q = wl[i];
        const float4* qr = (const float4*)(x + (size_t)q * 128);
        float a0 = 0.f, a1 = 0.f, a2 = 0.f, a3 = 0.f;
#pragma unroll 8
        for (int c4 = 0; c4 < 32; ++c4) {
            float4 qv = qr[c4];            // broadcast (same addr all lanes)
            float4 cv = cr[c4];
            a0 = fmaf(qv.x, cv.x, a0);
            a1 = fmaf(qv.y, cv.y, a1);
            a2 = fmaf(qv.z, cv.z, a2);
            a3 = fmaf(qv.w, cv.w, a3);
        }
        float dot = (a0 + a1) + (a2 + a3);
        float score = fmaf(-2.0f, dot, mycsq);
        unsigned long long key =
            ((unsigned long long)fmap(score) << 32) | (unsigned)tid;
#pragma unroll
        for (int d = 1; d < 64; d <<= 1) {
            unsigned long long o = __shfl_xor(key, d);
            key = o < key ? o : key;
        }
        if (lane == 0) sP[wave] = key;
        __syncthreads();
        if (tid == 0) {
            unsigned long long b = sP[0];
            unsigned long long o;
            o = sP[1]; b = o < b ? o : b;
            o = sP[2]; b = o < b ? o : b;
            o = sP[3]; b = o < b ? o : b;
            out[q] = (int)(unsigned)(b & 0xFFFFFFFFull);
        }
        __syncthreads();
    }
}

extern "C" void kernel_launch(void* const* d_in, const int* in_sizes, int n_in,
                              void* d_out, int out_size, void* d_ws, size_t ws_size,
                              hipStream_t stream) {
    const float* x = (const float*)d_in[0];
    const float* cb = (const float*)d_in[1];
    int* out = (int*)d_out;

    char* ws = (char*)d_ws;
    int* cnt = (int*)(ws + CNT_OFF);
    float* csq = (float*)(ws + CSQ_OFF);
    __bf16* cbB = (__bf16*)(ws + CBB_OFF);
    int* wl = (int*)(ws + WL_OFF);

    const int M = in_sizes[0] / 128;     // 131072

    knn_prep<<<32, 256, 0, stream>>>(cb, cbB, csq, cnt);
    knn_mfma<<<M / 64, 256, 0, stream>>>(x, cbB, csq, out, cnt, wl);
    knn_refine<<<240, 256, 0, stream>>>(x, cb, csq, wl, cnt, out);
}